// Round 5
// baseline (1431.638 us; speedup 1.0000x reference)
//
#include <hip/hip_runtime.h>
#include <math.h>

#define TT 250
#define BT 256
#define HN 128
#define ON 20
#define KIN 700
#define NKT 22

// ws layout (float offsets): xin[250*256*128] | packed W hi | packed W lo
#define XIN_OFF 0
#define WPKH_OFF 8192000   // 45056 floats (90112 bf16)
#define WPKL_OFF 8237056   // 45056 floats

typedef __attribute__((ext_vector_type(8))) short bf16x8;
typedef __attribute__((ext_vector_type(4))) float f32x4;

__device__ __forceinline__ unsigned short bf16rne(float f) {
    unsigned u = __float_as_uint(f);
    unsigned r = u + 0x7fffu + ((u >> 16) & 1u);
    return (unsigned short)(r >> 16);
}
__device__ __forceinline__ void hilo(float v, short& h, short& l) {
    unsigned short hh = bf16rne(v);
    float vh = __uint_as_float((unsigned)hh << 16);
    h = (short)hh;
    l = (short)bf16rne(v - vh);
}

// ---------------------------------------------------------------------------
// pack w_ih1 (700x128, zero-pad K to 704) into MFMA B-frag order, hi/lo bf16.
// ---------------------------------------------------------------------------
__global__ __launch_bounds__(256) void packw(const float* __restrict__ w,
                                             unsigned short* __restrict__ ph,
                                             unsigned short* __restrict__ pl) {
    int i = blockIdx.x * 256 + threadIdx.x;   // 352*256 = 90112 = 704*128
    int k = i >> 7, c = i & 127;
    float v = (k < KIN) ? w[k * HN + c] : 0.f;
    short h, l;
    hilo(v, h, l);
    int dst = (((k >> 5) * 8 + (c >> 4)) * 64 + (((k >> 3) & 3) * 16 + (c & 15))) * 8 + (k & 7);
    ph[dst] = (unsigned short)h;
    pl[dst] = (unsigned short)l;
}

// ---------------------------------------------------------------------------
// input projection via MFMA. B-frags staged per-kt in LDS (single-barrier
// double buffer) so B traffic is per-block, not per-wave. MFMA-bound.
// ---------------------------------------------------------------------------
__global__ __launch_bounds__(256) void gemm_in(const float* __restrict__ x,
        const bf16x8* __restrict__ wph, const bf16x8* __restrict__ wpl,
        const float* __restrict__ bias1, const float* __restrict__ bias2,
        float* __restrict__ xin) {
    __shared__ __align__(16) short Bs[2][2][4096];   // [buf][hi/lo][8KB]
    const int tid = threadIdx.x;
    const int w = tid >> 6, lane = tid & 63;
    const int q = lane >> 4, li = lane & 15;
    const long mrow = (long)blockIdx.x * 64 + w * 16 + li;
    const float* xr = x + mrow * KIN + q * 8;

    float b12[8];
#pragma unroll
    for (int nt = 0; nt < 8; nt++) b12[nt] = bias1[nt * 16 + li] + bias2[nt * 16 + li];

    f32x4 acc[8];
#pragma unroll
    for (int nt = 0; nt < 8; nt++) acc[nt] = (f32x4){0.f, 0.f, 0.f, 0.f};

    {   // prestage kt=0
        bf16x8* dh = (bf16x8*)Bs[0][0];
        bf16x8* dl = (bf16x8*)Bs[0][1];
        dh[tid] = wph[tid]; dh[tid + 256] = wph[tid + 256];
        dl[tid] = wpl[tid]; dl[tid + 256] = wpl[tid + 256];
    }
    __syncthreads();

    for (int kt = 0; kt < NKT; kt++) {
        const int cur = kt & 1;
        const bool more = (kt + 1 < NKT);
        bf16x8 nh0, nh1, nl0, nl1;
        if (more) {
            const int base = (kt + 1) * 512 + tid;
            nh0 = wph[base]; nh1 = wph[base + 256];
            nl0 = wpl[base]; nl1 = wpl[base + 256];
        }
        float av[8];
        *(float4*)&av[0] = *(const float4*)(xr + kt * 32);
        if (kt == NKT - 1 && q == 3) { av[4] = 0.f; av[5] = 0.f; av[6] = 0.f; av[7] = 0.f; }
        else *(float4*)&av[4] = *(const float4*)(xr + kt * 32 + 4);
        bf16x8 ah, al;
#pragma unroll
        for (int j = 0; j < 8; j++) { short h, l; hilo(av[j], h, l); ah[j] = h; al[j] = l; }

        const bf16x8* bh = (const bf16x8*)Bs[cur][0];
        const bf16x8* bl = (const bf16x8*)Bs[cur][1];
#pragma unroll
        for (int nt = 0; nt < 8; nt++) {
            bf16x8 vh = bh[nt * 64 + lane];
            bf16x8 vl = bl[nt * 64 + lane];
            acc[nt] = __builtin_amdgcn_mfma_f32_16x16x32_bf16(ah, vh, acc[nt], 0, 0, 0);
            acc[nt] = __builtin_amdgcn_mfma_f32_16x16x32_bf16(al, vh, acc[nt], 0, 0, 0);
            acc[nt] = __builtin_amdgcn_mfma_f32_16x16x32_bf16(ah, vl, acc[nt], 0, 0, 0);
        }
        if (more) {
            bf16x8* dh = (bf16x8*)Bs[cur ^ 1][0];
            bf16x8* dl = (bf16x8*)Bs[cur ^ 1][1];
            dh[tid] = nh0; dh[tid + 256] = nh1;
            dl[tid] = nl0; dl[tid + 256] = nl1;
        }
        __syncthreads();
    }

#pragma unroll
    for (int r = 0; r < 4; r++) {
        int m = blockIdx.x * 64 + w * 16 + q * 4 + r;
        int bq = (int)(((unsigned long long)m * 67109ull) >> 24);  // m/250
        int tt = m - bq * 250;
        float* dst = xin + ((size_t)tt * BT + bq) * HN;
#pragma unroll
        for (int nt = 0; nt < 8; nt++) dst[nt * 16 + li] = acc[nt][r] + b12[nt];
    }
}

// ---------------------------------------------------------------------------
// scan v7: 16 blocks x 1024 thr (16 waves, 4/SIMD). Waves 0-7 = hi-half
// weights for col-group w; waves 8-15 = lo-half for group w-8 (partials via
// LDS). Skewed schedule: segment Y(t) = ALL MFMAs (A-operands are spikes
// published at B1); segment X(t) = both LIF updates + om/softmax (consumes
// reg accs + LDS partials published at B2). 2 barriers/step, balanced
// 52 MFMA/SIMD in Y, pure VALU in X. xin(t+1) prefetched at Y-top.
// ---------------------------------------------------------------------------
#define PST 20   // partial-buffer col stride (floats)

__global__ __launch_bounds__(1024) void snn_scan(
    const float* __restrict__ xin, const float* __restrict__ mask,
    const float* __restrict__ w_h1h1, const float* __restrict__ w_h1h2,
    const float* __restrict__ b_h1h2, const float* __restrict__ w_h2h2,
    const float* __restrict__ b_h2h2, const float* __restrict__ w_h2o,
    const float* __restrict__ b_h2o, const float* __restrict__ tau_adp1,
    const float* __restrict__ tau_adp2, const float* __restrict__ taum1,
    const float* __restrict__ taum2, const float* __restrict__ taumo,
    const float* __restrict__ h1m0, const float* __restrict__ h2m0,
    const float* __restrict__ om0, float* __restrict__ out) {

    __shared__ __align__(16) unsigned short sF1[2048];  // S1 spike A-frags
    __shared__ __align__(16) unsigned short sF2[2048];  // S2 spike A-frags
    __shared__ __align__(16) float P11[HN * PST];       // lo partials, [col][row]
    __shared__ __align__(16) float P12[HN * PST];
    __shared__ __align__(16) float P22[HN * PST];
    __shared__ __align__(16) float Ohi[ON * PST];       // WHO partials
    __shared__ __align__(16) float Olo[ON * PST];
    __shared__ float red[16];

    const int tid = threadIdx.x;
    const int w = tid >> 6, lane = tid & 63;
    const int q = lane >> 4, li = lane & 15;
    const bool ishi = (w < 8);
    const int g = w & 7;
    const int col = g * 16 + li;
    const int r0 = blockIdx.x * 16;

    // ---- weight fragments: hi waves keep hi half, lo waves keep lo half ----
    bf16x8 f11[4], f12[4], f22[4], fO[4];
    const bool whoW = (w >= 12);
    const int ocol = (w < 14) ? li : 16 + li;   // w12/13: nt0, w14/15: nt1
    const bool oval = whoW && (ocol < ON);
    const bool oHi = (w == 12) || (w == 14);
    float pn = 0.f;
#pragma unroll
    for (int kt = 0; kt < 4; kt++) {
#pragma unroll
        for (int j = 0; j < 8; j++) {
            const int k = kt * 32 + q * 8 + j;
            const int idx = k * HN + col;
            float v11 = w_h1h1[idx] * mask[idx];
            float v22 = w_h2h2[idx] * mask[HN * HN + idx];
            float v12 = w_h1h2[idx];
            if (ishi) pn += fabsf(v11) + fabsf(v22);
            short h, l;
            hilo(v11, h, l); f11[kt][j] = ishi ? h : l;
            hilo(v22, h, l); f22[kt][j] = ishi ? h : l;
            hilo(v12, h, l); f12[kt][j] = ishi ? h : l;
            float vO = oval ? w_h2o[k * ON + ocol] : 0.f;
            hilo(vO, h, l); fO[kt][j] = oHi ? h : l;
        }
    }

    // ---- hi-wave LIF state ----
    float a1 = 0.f, r1c = 0.f, a2 = 0.f, r2c = 0.f, cc2 = 0.f;
    float h1m[4], h2m[4], b1a[4], b2a[4], c1[4], c2n[4], xt[4];
    unsigned s1bits = 0, s2bits = 0;
    if (ishi) {
        a1 = expf(-1.f / taum1[col]);
        r1c = expf(-1.f / tau_adp1[col]);
        a2 = expf(-1.f / taum2[col]);
        r2c = expf(-1.f / tau_adp2[col]);
        cc2 = b_h1h2[col] + b_h2h2[col];
#pragma unroll
        for (int r = 0; r < 4; r++) {
            h1m[r] = h1m0[(r0 + q * 4 + r) * HN + col];
            h2m[r] = h2m0[(r0 + q * 4 + r) * HN + col];
            b1a[r] = 0.01f; b2a[r] = 0.01f; c1[r] = 0.f; c2n[r] = 0.f;
            xt[r] = xin[(size_t)(r0 + q * 4 + r) * HN + col];   // t = 0
        }
    }
    // ---- wave-15 readout/softmax state ----
    const int sm = lane >> 2, ob = (lane & 3) * 5;
    float om[5], accs[5], aoc[5], bjoc[5];
    if (w == 15) {
#pragma unroll
        for (int i = 0; i < 5; i++) {
            aoc[i] = expf(-1.f / taumo[ob + i]);
            bjoc[i] = b_h2o[ob + i];
            om[i] = om0[(r0 + sm) * ON + ob + i];
            accs[i] = 0.f;
        }
    }

    // ---- zero LDS ----
    ((unsigned*)sF1)[tid] = 0u;
    ((unsigned*)sF2)[tid] = 0u;
    for (int i = tid; i < HN * PST; i += 1024) { P11[i] = 0.f; P12[i] = 0.f; P22[i] = 0.f; }
    for (int i = tid; i < ON * PST; i += 1024) { Ohi[i] = 0.f; Olo[i] = 0.f; }

    // ---- A_norm (hi waves hold each element once) ----
#pragma unroll
    for (int off = 32; off > 0; off >>= 1) pn += __shfl_down(pn, off);
    if (lane == 0) red[w] = pn;
    __syncthreads();
    if (tid == 0 && blockIdx.x == 0) {
        float s = 0.f;
#pragma unroll
        for (int i = 0; i < 8; i++) s += red[i];
        out[70656] = s;
    }

    // spike frag write index (hi waves): lane's 4 rows at +r*8
    const int wbase = (w >> 1) * 512 + ((((2 * w + (li >> 3)) & 3) * 16 + q * 4) * 8) + (li & 7);
    const int pidx = col * PST + q * 4;
    const bf16x8* s1v = (const bf16x8*)sF1;
    const bf16x8* s2v = (const bf16x8*)sF2;
    const unsigned short ONE = 0x3F80u;

    f32x4 aI = {0.f, 0.f, 0.f, 0.f}, aJ = {0.f, 0.f, 0.f, 0.f}, aG = {0.f, 0.f, 0.f, 0.f};

    for (int t = 0; t < TT; t++) {
        // ================= X(t): updates (pure VALU) =================
        if (ishi) {
            if (t >= 1) {   // update-2 for step t-1 -> S2(t-1)
                float4 pj = *(float4*)&P12[pidx];
                float4 pg = *(float4*)&P22[pidx];
#pragma unroll
                for (int r = 0; r < 4; r++) {
                    const float sv = (float)((s2bits >> r) & 1u);
                    const float i2 = aJ[r] + pj[r] + aG[r] + pg[r] + cc2;
                    b2a[r] = r2c * b2a[r] + (1.f - r2c) * sv;
                    const float B = 0.01f + 1.8f * b2a[r];
                    h2m[r] = a2 * h2m[r] + (1.f - a2) * i2 - B * sv;
                    const bool sp = (h2m[r] - B) > 0.f;
                    s2bits = sp ? (s2bits | (1u << r)) : (s2bits & ~(1u << r));
                    c2n[r] += sp ? 1.f : 0.f;
                    sF2[wbase + r * 8] = sp ? ONE : (unsigned short)0;
                }
            }
            {   // update-1 for step t -> S1(t)
                float4 pi = *(float4*)&P11[pidx];
#pragma unroll
                for (int r = 0; r < 4; r++) {
                    const float sv = (float)((s1bits >> r) & 1u);
                    const float i1 = xt[r] + aI[r] + pi[r];
                    b1a[r] = r1c * b1a[r] + (1.f - r1c) * sv;
                    const float B = 0.01f + 1.8f * b1a[r];
                    h1m[r] = a1 * h1m[r] + (1.f - a1) * i1 - B * sv;
                    const bool sp = (h1m[r] - B) > 0.f;
                    s1bits = sp ? (s1bits | (1u << r)) : (s1bits & ~(1u << r));
                    c1[r] += sp ? 1.f : 0.f;
                    sF1[wbase + r * 8] = sp ? ONE : (unsigned short)0;
                }
            }
        } else if (w == 15 && t >= 2) {
            // om update for step t-2 (+ softmax accumulate)
            float e[5];
#pragma unroll
            for (int i = 0; i < 5; i++) {
                const float io = bjoc[i] + Ohi[(ob + i) * PST + sm] + Olo[(ob + i) * PST + sm];
                om[i] = aoc[i] * om[i] + (1.f - aoc[i]) * io;
            }
            if (t >= 13) {
                float mx = om[0];
#pragma unroll
                for (int i = 1; i < 5; i++) mx = fmaxf(mx, om[i]);
                mx = fmaxf(mx, __shfl_xor(mx, 1));
                mx = fmaxf(mx, __shfl_xor(mx, 2));
                float se = 0.f;
#pragma unroll
                for (int i = 0; i < 5; i++) { e[i] = __expf(om[i] - mx); se += e[i]; }
                se += __shfl_xor(se, 1);
                se += __shfl_xor(se, 2);
                const float inv = 1.f / se;
#pragma unroll
                for (int i = 0; i < 5; i++) accs[i] += e[i] * inv;
            }
        }
        __syncthreads();   // B1: S1(t), S2(t-1) frags published

        // ================= Y(t): all MFMAs =================
        if (ishi) {
            // prefetch xin for t+1 (consumed in X(t+1); window = all of Y)
            const int tn = (t < TT - 1) ? t + 1 : t;
#pragma unroll
            for (int r = 0; r < 4; r++)
                xt[r] = xin[((size_t)tn * BT + r0 + q * 4 + r) * HN + col];
            aI = (f32x4){0.f, 0.f, 0.f, 0.f};
            aJ = (f32x4){0.f, 0.f, 0.f, 0.f};
            aG = (f32x4){0.f, 0.f, 0.f, 0.f};
#pragma unroll
            for (int kt = 0; kt < 4; kt++) {
                bf16x8 s1f = s1v[kt * 64 + lane];
                bf16x8 s2f = s2v[kt * 64 + lane];
                aI = __builtin_amdgcn_mfma_f32_16x16x32_bf16(s1f, f11[kt], aI, 0, 0, 0);
                aJ = __builtin_amdgcn_mfma_f32_16x16x32_bf16(s1f, f12[kt], aJ, 0, 0, 0);
                aG = __builtin_amdgcn_mfma_f32_16x16x32_bf16(s2f, f22[kt], aG, 0, 0, 0);
            }
        } else {
            f32x4 pI = {0.f, 0.f, 0.f, 0.f}, pJ = {0.f, 0.f, 0.f, 0.f}, pG = {0.f, 0.f, 0.f, 0.f};
#pragma unroll
            for (int kt = 0; kt < 4; kt++) {
                bf16x8 s1f = s1v[kt * 64 + lane];
                bf16x8 s2f = s2v[kt * 64 + lane];
                pI = __builtin_amdgcn_mfma_f32_16x16x32_bf16(s1f, f11[kt], pI, 0, 0, 0);
                pJ = __builtin_amdgcn_mfma_f32_16x16x32_bf16(s1f, f12[kt], pJ, 0, 0, 0);
                pG = __builtin_amdgcn_mfma_f32_16x16x32_bf16(s2f, f22[kt], pG, 0, 0, 0);
            }
            *(float4*)&P11[pidx] = *(float4*)&pI;
            *(float4*)&P12[pidx] = *(float4*)&pJ;
            *(float4*)&P22[pidx] = *(float4*)&pG;
            if (whoW) {
                f32x4 pO = {0.f, 0.f, 0.f, 0.f};
#pragma unroll
                for (int kt = 0; kt < 4; kt++) {
                    bf16x8 s2f = s2v[kt * 64 + lane];
                    pO = __builtin_amdgcn_mfma_f32_16x16x32_bf16(s2f, fO[kt], pO, 0, 0, 0);
                }
                if (oval) {
                    float* O = oHi ? Ohi : Olo;
                    *(float4*)&O[ocol * PST + q * 4] = *(float4*)&pO;
                }
            }
        }
        __syncthreads();   // B2: partials published
    }

    // ================= tail =================
    // X-tail-1: update-2(249) -> S2(249); om(248)+softmax on w15
    if (ishi) {
        float4 pj = *(float4*)&P12[pidx];
        float4 pg = *(float4*)&P22[pidx];
#pragma unroll
        for (int r = 0; r < 4; r++) {
            const float sv = (float)((s2bits >> r) & 1u);
            const float i2 = aJ[r] + pj[r] + aG[r] + pg[r] + cc2;
            b2a[r] = r2c * b2a[r] + (1.f - r2c) * sv;
            const float B = 0.01f + 1.8f * b2a[r];
            h2m[r] = a2 * h2m[r] + (1.f - a2) * i2 - B * sv;
            const bool sp = (h2m[r] - B) > 0.f;
            c2n[r] += sp ? 1.f : 0.f;
            sF2[wbase + r * 8] = sp ? ONE : (unsigned short)0;
        }
    } else if (w == 15) {
        float e[5];
#pragma unroll
        for (int i = 0; i < 5; i++) {
            const float io = bjoc[i] + Ohi[(ob + i) * PST + sm] + Olo[(ob + i) * PST + sm];
            om[i] = aoc[i] * om[i] + (1.f - aoc[i]) * io;
        }
        float mx = om[0];
#pragma unroll
        for (int i = 1; i < 5; i++) mx = fmaxf(mx, om[i]);
        mx = fmaxf(mx, __shfl_xor(mx, 1));
        mx = fmaxf(mx, __shfl_xor(mx, 2));
        float se = 0.f;
#pragma unroll
        for (int i = 0; i < 5; i++) { e[i] = __expf(om[i] - mx); se += e[i]; }
        se += __shfl_xor(se, 1);
        se += __shfl_xor(se, 2);
        const float inv = 1.f / se;
#pragma unroll
        for (int i = 0; i < 5; i++) accs[i] += e[i] * inv;
    }
    __syncthreads();
    // Y-tail: WHO . S2(249)
    if (whoW) {
        f32x4 pO = {0.f, 0.f, 0.f, 0.f};
#pragma unroll
        for (int kt = 0; kt < 4; kt++) {
            bf16x8 s2f = s2v[kt * 64 + lane];
            pO = __builtin_amdgcn_mfma_f32_16x16x32_bf16(s2f, fO[kt], pO, 0, 0, 0);
        }
        if (oval) {
            float* O = oHi ? Ohi : Olo;
            *(float4*)&O[ocol * PST + q * 4] = *(float4*)&pO;
        }
    }
    __syncthreads();
    // X-tail-2: om(249) + softmax + store outputs
    if (w == 15) {
        float e[5];
#pragma unroll
        for (int i = 0; i < 5; i++) {
            const float io = bjoc[i] + Ohi[(ob + i) * PST + sm] + Olo[(ob + i) * PST + sm];
            om[i] = aoc[i] * om[i] + (1.f - aoc[i]) * io;
        }
        float mx = om[0];
#pragma unroll
        for (int i = 1; i < 5; i++) mx = fmaxf(mx, om[i]);
        mx = fmaxf(mx, __shfl_xor(mx, 1));
        mx = fmaxf(mx, __shfl_xor(mx, 2));
        float se = 0.f;
#pragma unroll
        for (int i = 0; i < 5; i++) { e[i] = __expf(om[i] - mx); se += e[i]; }
        se += __shfl_xor(se, 1);
        se += __shfl_xor(se, 2);
        const float inv = 1.f / se;
#pragma unroll
        for (int i = 0; i < 5; i++)
            out[(r0 + sm) * ON + ob + i] = accs[i] + e[i] * inv;
    }
    if (ishi) {
#pragma unroll
        for (int r = 0; r < 4; r++) {
            out[5120 + (r0 + q * 4 + r) * HN + col] = c1[r] * (1.f / 250.f);
            out[37888 + (r0 + q * 4 + r) * HN + col] = c2n[r] * (1.f / 250.f);
        }
    }
}

// ---------------------------------------------------------------------------
extern "C" void kernel_launch(void* const* d_in, const int* in_sizes, int n_in,
                              void* d_out, int out_size, void* d_ws, size_t ws_size,
                              hipStream_t stream) {
    const float* x        = (const float*)d_in[0];
    const float* mask     = (const float*)d_in[1];
    const float* w_ih1    = (const float*)d_in[2];
    const float* b_ih1    = (const float*)d_in[3];
    const float* w_h1h1   = (const float*)d_in[4];
    const float* b_h1h1   = (const float*)d_in[5];
    const float* w_h1h2   = (const float*)d_in[6];
    const float* b_h1h2   = (const float*)d_in[7];
    const float* w_h2h2   = (const float*)d_in[8];
    const float* b_h2h2   = (const float*)d_in[9];
    const float* w_h2o    = (const float*)d_in[10];
    const float* b_h2o    = (const float*)d_in[11];
    const float* tau_adp1 = (const float*)d_in[12];
    const float* tau_adp2 = (const float*)d_in[13];
    const float* taum1    = (const float*)d_in[14];
    const float* taum2    = (const float*)d_in[15];
    const float* taumo    = (const float*)d_in[16];
    const float* h1m0     = (const float*)d_in[17];
    const float* h2m0     = (const float*)d_in[18];
    const float* om0      = (const float*)d_in[19];
    float* out = (float*)d_out;
    float* ws  = (float*)d_ws;

    float* xin = ws + XIN_OFF;
    unsigned short* wph = (unsigned short*)(ws + WPKH_OFF);
    unsigned short* wpl = (unsigned short*)(ws + WPKL_OFF);

    packw<<<352, 256, 0, stream>>>(w_ih1, wph, wpl);
    gemm_in<<<1000, 256, 0, stream>>>(x, (const bf16x8*)wph, (const bf16x8*)wpl,
                                      b_ih1, b_h1h1, xin);
    snn_scan<<<16, 1024, 0, stream>>>(xin, mask, w_h1h1, w_h1h2, b_h1h2, w_h2h2,
                                      b_h2h2, w_h2o, b_h2o, tau_adp1, tau_adp2,
                                      taum1, taum2, taumo, h1m0, h2m0, om0, out);
}